// Round 6
// baseline (379.177 us; speedup 1.0000x reference)
//
#include <hip/hip_runtime.h>

// Problem constants
#define B_   4
#define L_   4096
#define D_   1024
#define ROWS (B_ * L_)     // 16384
#define K2   (2 * D_)      // 2048
#define BLD  (ROWS * D_)   // 16777216
#define CH   32            // chunk length for scan
#define NC   128           // chunks per sequence (CH*NC == L_)

typedef __attribute__((ext_vector_type(8))) short s8v;   // 8 x bf16
typedef __attribute__((ext_vector_type(4))) float f4v;   // 4 x f32 acc

__device__ __forceinline__ unsigned short f2bf(float f) {
    unsigned int u = __float_as_uint(f);
    u += 0x7FFFu + ((u >> 16) & 1u);
    return (unsigned short)(u >> 16);
}
__device__ __forceinline__ float sigmoidf_(float v) {
    return 1.0f / (1.0f + __expf(-v));
}
__device__ __forceinline__ void llds16(const void* g, void* l) {
    __builtin_amdgcn_global_load_lds(
        (const __attribute__((address_space(1))) unsigned int*)(g),
        (__attribute__((address_space(3))) unsigned int*)(l),
        16, 0, 0);
}

// ---------------- preprocessing ----------------

// Fused: blocks [0,512) = per-chunk partial sums (CH=32); [512,4608) = W->bf16.
__global__ void prep1(const float4* __restrict__ x4, float4* __restrict__ part4,
                      const float4* __restrict__ W, ushort4* __restrict__ Wbf) {
    int bid = blockIdx.x;
    int t = threadIdx.x;
    if (bid < 512) {
        int c = bid & 127, b = bid >> 7;
        const float4* p = x4 + ((size_t)(b * L_ + c * CH) * 256 + t);
        float4 s; s.x = 0.f; s.y = 0.f; s.z = 0.f; s.w = 0.f;
#pragma unroll 8
        for (int i = 0; i < CH; ++i) {
            float4 v = p[(size_t)i * 256];
            s.x += v.x; s.y += v.y; s.z += v.z; s.w += v.w;
        }
        part4[(size_t)bid * 256 + t] = s;   // bid == b*NC + c
    } else {
        int i = (bid - 512) * 256 + t;     // [0, 1048576)
        float4 v = W[i];
        ushort4 o; o.x = f2bf(v.x); o.y = f2bf(v.y); o.z = f2bf(v.z); o.w = f2bf(v.w);
        Wbf[i] = o;
    }
}

// Fused chunk-scan + apply. part array = 2 MB -> prefix re-reads are L2/L3 hits.
__global__ void apply_scan(const float4* __restrict__ x4, const float4* __restrict__ part4,
                           float4* __restrict__ avg4, ushort4* __restrict__ A4) {
    __shared__ float inv[CH];
    int bid = blockIdx.x;            // [0,512)
    int c = bid & 127, b = bid >> 7;
    int t = threadIdx.x;
    if (t < CH) inv[t] = 1.0f / (float)(c * CH + t + 1);

    float4 s; s.x = 0.f; s.y = 0.f; s.z = 0.f; s.w = 0.f;
    for (int cc = 0; cc < c; ++cc) {
        float4 v = part4[((size_t)(b * NC + cc)) * 256 + t];
        s.x += v.x; s.y += v.y; s.z += v.z; s.w += v.w;
    }
    __syncthreads();

    size_t row0 = (size_t)b * L_ + (size_t)c * CH;
    const float4* px = x4 + (row0 * 256 + t);
    float4*       pa = avg4 + (row0 * 256 + t);
    ushort4*      pA = A4 + (row0 * 512 + t);
#pragma unroll 4
    for (int i = 0; i < CH; ++i) {
        float4 v = px[(size_t)i * 256];
        s.x += v.x; s.y += v.y; s.z += v.z; s.w += v.w;
        float r = inv[i];
        float4 av; av.x = s.x * r; av.y = s.y * r; av.z = s.z * r; av.w = s.w * r;
        pa[(size_t)i * 256] = av;
        ushort4 ux; ux.x = f2bf(v.x);  ux.y = f2bf(v.y);  ux.z = f2bf(v.z);  ux.w = f2bf(v.w);
        ushort4 ua; ua.x = f2bf(av.x); ua.y = f2bf(av.y); ua.z = f2bf(av.z); ua.w = f2bf(av.w);
        pA[(size_t)i * 512]       = ux;
        pA[(size_t)i * 512 + 256] = ua;
    }
}

// ---------------- 8-wave GEMM + gating, merged single-phase per K-tile ----------------
// Block: 512 threads = 8 waves (4M x 2N). Output: 256 rows x 128 cols x 2 halves.
// BK=32. LDS: 4-buffer ring (128 KiB), 3-tile lead, counted vmcnt(8).
// ONE phase per tau: {12 ds_read + 4 llds16 -> vmcnt(8) -> barrier ->
// lgkmcnt(0) -> 32 MFMA -> barrier}. Halves barrier crossings (4->2) and lgkm
// drains (2->1) per tau vs R4. Ring safety: closing barrier after MFMA means
// every wave's reads of tile tau drained (own lgkmcnt(0)) before any wave can
// issue tile tau+4's DMA into the same buffer.
// LDS swizzle (verified conflict-free): phys_byte = logical ^ (((row>>1)&3)<<4);
// staging applies inverse granule perm q ^ ((q>>3)&3) to the GLOBAL source.
__global__ __launch_bounds__(512, 2) void gemm_gated8(
        const unsigned short* __restrict__ Abf, const unsigned short* __restrict__ Wbf,
        const float* __restrict__ x, const float* __restrict__ avg,
        const float* __restrict__ bg, float* __restrict__ out) {
    __shared__ __attribute__((aligned(16))) unsigned short S[4 * 2 * 8192]; // 128 KiB

    const int t    = threadIdx.x;          // 0..511
    const int w    = t >> 6;               // 0..7
    const int lane = t & 63;
    const int wm = w >> 1, wn = w & 1;     // 4M x 2N wave grid
    const int quad = lane >> 4, lcol = lane & 15;

    const int bid = blockIdx.x;            // 512 blocks, 512%8==0 -> bijective
    const int swz = (bid & 7) * 64 + (bid >> 3);     // XCD-contiguous
    const int tileN = swz & 7, tileM = swz >> 3;
    const int row0 = tileM * 256, col0 = tileN * 128;

    f4v acc0[4][4], acc1[4][4];
#pragma unroll
    for (int i = 0; i < 4; ++i)
#pragma unroll
        for (int j = 0; j < 4; ++j)
#pragma unroll
            for (int r = 0; r < 4; ++r) { acc0[i][j][r] = 0.f; acc1[i][j][r] = 0.f; }

    // ---- staging precompute: thread t owns granules q = t and q = 512+t ----
    const int qA0 = t, qA1 = 512 + t;
    const int p0 = qA0 ^ ((qA0 >> 3) & 3);
    const int p1 = qA1 ^ ((qA1 >> 3) & 3);
    const int m0 = p0 >> 2, k0e = (p0 & 3) * 8;
    const int m1 = p1 >> 2, k1e = (p1 & 3) * 8;
    const unsigned short* gA0 = Abf + (size_t)(row0 + m0) * K2 + k0e;
    const unsigned short* gA1 = Abf + (size_t)(row0 + m1) * K2 + k1e;
    const unsigned short* gB0 = Wbf + (size_t)(col0 + (m0 & 127) + (m0 >> 7) * 1024) * K2 + k0e;
    const unsigned short* gB1 = Wbf + (size_t)(col0 + (m1 & 127) + (m1 >> 7) * 1024) * K2 + k1e;

    // ---- LDS read offsets (ushort index), swizzled: byte ^= ((row>>1)&3)<<4 ----
    int aoff[4], boff[2][4];
#pragma unroll
    for (int i = 0; i < 4; ++i) {
        int ar = wm * 64 + i * 16 + lcol;
        aoff[i] = ((ar * 64 + quad * 16) ^ (((ar >> 1) & 3) << 4)) >> 1;
    }
#pragma unroll
    for (int h = 0; h < 2; ++h)
#pragma unroll
        for (int j = 0; j < 4; ++j) {
            int br = h * 128 + wn * 64 + j * 16 + lcol;
            boff[h][j] = ((br * 64 + quad * 16) ^ (((br >> 1) & 3) << 4)) >> 1;
        }

    // ---- prologue: stage tiles 0,1,2 into buffers 0,1,2 ----
#pragma unroll
    for (int tt = 0; tt < 3; ++tt) {
        unsigned short* dA = S + tt * 16384;
        unsigned short* dB = S + tt * 16384 + 8192;
        llds16(gA0 + tt * 32, dA + qA0 * 8);
        llds16(gA1 + tt * 32, dA + qA1 * 8);
        llds16(gB0 + tt * 32, dB + qA0 * 8);
        llds16(gB1 + tt * 32, dB + qA1 * 8);
    }
    asm volatile("s_waitcnt vmcnt(8)" ::: "memory");  // tile 0 landed; 1,2 in flight
    __builtin_amdgcn_s_barrier();

    // ---- main loop: taus 0..60, staging always active ----
    for (int tau = 0; tau < 61; ++tau) {
        const unsigned short* bA = S + (tau & 3) * 16384;
        const unsigned short* bB = bA + 8192;
        unsigned short* dA = S + ((tau + 3) & 3) * 16384;
        unsigned short* dB = dA + 8192;
        const int ko = (tau + 3) * 32;

        s8v af[4], bf0[4], bf1[4];
#pragma unroll
        for (int i = 0; i < 4; ++i) af[i] = *(const s8v*)(bA + aoff[i]);
#pragma unroll
        for (int j = 0; j < 4; ++j) {
            bf0[j] = *(const s8v*)(bB + boff[0][j]);
            bf1[j] = *(const s8v*)(bB + boff[1][j]);
        }
        llds16(gA0 + ko, dA + qA0 * 8);
        llds16(gA1 + ko, dA + qA1 * 8);
        llds16(gB0 + ko, dB + qA0 * 8);
        llds16(gB1 + ko, dB + qA1 * 8);
        asm volatile("s_waitcnt vmcnt(8)" ::: "memory");  // retire tile tau+1's loads
        __builtin_amdgcn_s_barrier();
        asm volatile("s_waitcnt lgkmcnt(0)");
        __builtin_amdgcn_sched_barrier(0);
        __builtin_amdgcn_s_setprio(1);
#pragma unroll
        for (int i = 0; i < 4; ++i)
#pragma unroll
            for (int j = 0; j < 4; ++j) {
                acc0[i][j] = __builtin_amdgcn_mfma_f32_16x16x32_bf16(af[i], bf0[j], acc0[i][j], 0, 0, 0);
                acc1[i][j] = __builtin_amdgcn_mfma_f32_16x16x32_bf16(af[i], bf1[j], acc1[i][j], 0, 0, 0);
            }
        __builtin_amdgcn_s_setprio(0);
        __builtin_amdgcn_s_barrier();
    }

    // ---- tail: taus 61..63, no staging, full drain ----
    for (int tau = 61; tau < 64; ++tau) {
        const unsigned short* bA = S + (tau & 3) * 16384;
        const unsigned short* bB = bA + 8192;

        s8v af[4], bf0[4], bf1[4];
#pragma unroll
        for (int i = 0; i < 4; ++i) af[i] = *(const s8v*)(bA + aoff[i]);
#pragma unroll
        for (int j = 0; j < 4; ++j) {
            bf0[j] = *(const s8v*)(bB + boff[0][j]);
            bf1[j] = *(const s8v*)(bB + boff[1][j]);
        }
        asm volatile("s_waitcnt vmcnt(0)" ::: "memory");  // epilogue drain
        __builtin_amdgcn_s_barrier();
        asm volatile("s_waitcnt lgkmcnt(0)");
        __builtin_amdgcn_sched_barrier(0);
        __builtin_amdgcn_s_setprio(1);
#pragma unroll
        for (int i = 0; i < 4; ++i)
#pragma unroll
            for (int j = 0; j < 4; ++j) {
                acc0[i][j] = __builtin_amdgcn_mfma_f32_16x16x32_bf16(af[i], bf0[j], acc0[i][j], 0, 0, 0);
                acc1[i][j] = __builtin_amdgcn_mfma_f32_16x16x32_bf16(af[i], bf1[j], acc1[i][j], 0, 0, 0);
            }
        __builtin_amdgcn_s_setprio(0);
        __builtin_amdgcn_s_barrier();
    }

    // ---- epilogue: gating in-register. C/D: col = lane&15, row = quad*4+reg ----
    float b1v[4], b2v[4];
#pragma unroll
    for (int j = 0; j < 4; ++j) {
        int cc = col0 + wn * 64 + j * 16 + lcol;
        b1v[j] = bg[cc];
        b2v[j] = bg[1024 + cc];
    }
#pragma unroll
    for (int i = 0; i < 4; ++i) {
#pragma unroll
        for (int j = 0; j < 4; ++j) {
            int rr = row0 + wm * 64 + i * 16 + quad * 4;
            int cc = col0 + wn * 64 + j * 16 + lcol;
#pragma unroll
            for (int r = 0; r < 4; ++r) {
                size_t off = (size_t)(rr + r) * D_ + cc;
                float gi = sigmoidf_(acc0[i][j][r] + b1v[j]);
                float gf = sigmoidf_(acc1[i][j][r] + b2v[j]);
                out[off] = gi * x[off] + gf * avg[off];
            }
        }
    }
}

extern "C" void kernel_launch(void* const* d_in, const int* in_sizes, int n_in,
                              void* d_out, int out_size, void* d_ws, size_t ws_size,
                              hipStream_t stream) {
    const float* x  = (const float*)d_in[0];   // [4,4096,1024]
    const float* W  = (const float*)d_in[1];   // [2048,2048]
    const float* bg = (const float*)d_in[2];   // [2048]
    float* out = (float*)d_out;                // [BLD gating | BLD avg]
    float* avg = out + (size_t)BLD;

    char* ws = (char*)d_ws;
    unsigned short* Abf = (unsigned short*)(ws);                      // 64 MB [16384 x 2048] bf16
    unsigned short* Wbf = (unsigned short*)(ws + (size_t)67108864);   //  8 MB [2048 x 2048] bf16
    float4*         prt = (float4*)(ws + (size_t)75497472);           //  2 MB [B x NC x D] f32

    prep1<<<dim3(4608), dim3(256), 0, stream>>>((const float4*)x, prt,
                                                (const float4*)W, (ushort4*)Wbf);
    apply_scan<<<dim3(512), dim3(256), 0, stream>>>((const float4*)x, prt,
                                                    (float4*)avg, (ushort4*)Abf);
    gemm_gated8<<<dim3(512), dim3(512), 0, stream>>>(Abf, Wbf, x, avg, bg, out);
}

// Round 7
// 352.638 us; speedup vs baseline: 1.0753x; 1.0753x over previous
//
#include <hip/hip_runtime.h>

// Problem constants
#define B_   4
#define L_   4096
#define D_   1024
#define ROWS (B_ * L_)     // 16384
#define K2   (2 * D_)      // 2048
#define BLD  (ROWS * D_)   // 16777216
#define CH   64            // chunk length for scan
#define NC   64            // chunks per sequence

typedef __attribute__((ext_vector_type(8))) short s8v;   // 8 x bf16
typedef __attribute__((ext_vector_type(4))) float f4v;   // 4 x f32 acc

__device__ __forceinline__ unsigned short f2bf(float f) {
    unsigned int u = __float_as_uint(f);
    u += 0x7FFFu + ((u >> 16) & 1u);
    return (unsigned short)(u >> 16);
}
__device__ __forceinline__ float sigmoidf_(float v) {
    return 1.0f / (1.0f + __expf(-v));
}
__device__ __forceinline__ void llds16(const void* g, void* l) {
    __builtin_amdgcn_global_load_lds(
        (const __attribute__((address_space(1))) unsigned int*)(g),
        (__attribute__((address_space(3))) unsigned int*)(l),
        16, 0, 0);
}

// ---------------- preprocessing (R3 config: CH=64, fused W-conv) ----------------

__global__ void prep1(const float4* __restrict__ x4, float4* __restrict__ part4,
                      const float4* __restrict__ W, ushort4* __restrict__ Wbf) {
    int bid = blockIdx.x;
    int t = threadIdx.x;
    if (bid < 256) {
        int c = bid & 63, b = bid >> 6;
        const float4* p = x4 + ((size_t)(b * L_ + c * CH) * 256 + t);
        float4 s; s.x = 0.f; s.y = 0.f; s.z = 0.f; s.w = 0.f;
#pragma unroll 8
        for (int i = 0; i < CH; ++i) {
            float4 v = p[(size_t)i * 256];
            s.x += v.x; s.y += v.y; s.z += v.z; s.w += v.w;
        }
        part4[(size_t)bid * 256 + t] = s;
    } else {
        int i = (bid - 256) * 256 + t;     // [0, 1048576)
        float4 v = W[i];
        ushort4 o; o.x = f2bf(v.x); o.y = f2bf(v.y); o.z = f2bf(v.z); o.w = f2bf(v.w);
        Wbf[i] = o;
    }
}

__global__ void apply_scan(const float4* __restrict__ x4, const float4* __restrict__ part4,
                           float4* __restrict__ avg4, ushort4* __restrict__ A4) {
    __shared__ float inv[CH];
    int bid = blockIdx.x;            // [0,256)
    int c = bid & 63, b = bid >> 6;
    int t = threadIdx.x;
    if (t < CH) inv[t] = 1.0f / (float)(c * CH + t + 1);

    float4 s; s.x = 0.f; s.y = 0.f; s.z = 0.f; s.w = 0.f;
    for (int cc = 0; cc < c; ++cc) {
        float4 v = part4[((size_t)(b * NC + cc)) * 256 + t];
        s.x += v.x; s.y += v.y; s.z += v.z; s.w += v.w;
    }
    __syncthreads();

    size_t row0 = (size_t)b * L_ + (size_t)c * CH;
    const float4* px = x4 + (row0 * 256 + t);
    float4*       pa = avg4 + (row0 * 256 + t);
    ushort4*      pA = A4 + (row0 * 512 + t);
#pragma unroll 4
    for (int i = 0; i < CH; ++i) {
        float4 v = px[(size_t)i * 256];
        s.x += v.x; s.y += v.y; s.z += v.z; s.w += v.w;
        float r = inv[i];
        float4 av; av.x = s.x * r; av.y = s.y * r; av.z = s.z * r; av.w = s.w * r;
        pa[(size_t)i * 256] = av;
        ushort4 ux; ux.x = f2bf(v.x);  ux.y = f2bf(v.y);  ux.z = f2bf(v.z);  ux.w = f2bf(v.w);
        ushort4 ua; ua.x = f2bf(av.x); ua.y = f2bf(av.y); ua.z = f2bf(av.z); ua.w = f2bf(av.w);
        pA[(size_t)i * 512]       = ux;
        pA[(size_t)i * 512 + 256] = ua;
    }
}

// ---------------- 8-wave GEMM + gating, half-tau pipelined ----------------
// Block: 512 thr = 8 waves (4M x 2N). Tile: 256 rows x 128 cols x 2 halves.
// BK=32, 4-buffer LDS ring (128 KiB), 3-tile lead, counted vmcnt(8)/tau.
// R7: overlap LDS-reads with MFMA. Per tau:
//   H1: read bf1(tau) | stage tile tau+3 | vmcnt(8) | BARRIER#1 |
//       lgkm(4) -> MFMA acc0(af_c,bf0_c)
//   H2: prefetch af/bf0(tau+1) from ring buf (tau+1)&3 | lgkm(8) ->
//       MFMA acc1(af_c,bf1) | BARRIER#2
// Counted lgkm relies on in-order DS retirement; sched_barrier(0) pins each
// read group (rule #18). Fragments double-buffered with literal indices
// (rule #20) via x2-unrolled pair loop. Hazards: DMA-arrival->read ordered by
// vmcnt(8)+BARRIER#1 (tile tau+1 prefetch comes after); read-drain->DMA
// overwrite ordered by per-wave lgkm waits + BARRIER#2.
// LDS swizzle (verified conflict-free): byte ^= ((row>>1)&3)<<4; staging uses
// inverse granule perm q ^ ((q>>3)&3) on the GLOBAL source (rule #21).
#define TAU_ITER(CUR, NXT, TAU, DO_STAGE, DO_PF, VMSTR)                        \
  {                                                                            \
    const int tau_ = (TAU);                                                    \
    const unsigned short* bB_ = S + (tau_ & 3) * 16384 + 8192;                 \
    s8v b1f[4];                                                                \
    _Pragma("unroll")                                                          \
    for (int j = 0; j < 4; ++j)                                                \
      b1f[j] = *(const s8v*)(bB_ + boffb + 4096 + j * 512);                    \
    __builtin_amdgcn_sched_barrier(0);                                         \
    if (DO_STAGE) {                                                            \
      const int ko_ = (tau_ + 3) * 32;                                         \
      unsigned short* dA_ = S + ((tau_ + 3) & 3) * 16384;                      \
      llds16(gA0 + ko_, dA_ + qA0 * 8);                                        \
      llds16(gA0 + 262144 + ko_, dA_ + qA1 * 8);                               \
      llds16(gB0 + ko_, dA_ + 8192 + qA0 * 8);                                 \
      llds16(gB0 + 2097152 + ko_, dA_ + 8192 + qA1 * 8);                       \
    }                                                                          \
    asm volatile("s_waitcnt vmcnt(" VMSTR ")" ::: "memory");                   \
    __builtin_amdgcn_s_barrier();                                              \
    asm volatile("s_waitcnt lgkmcnt(4)");                                      \
    __builtin_amdgcn_sched_barrier(0);                                         \
    __builtin_amdgcn_s_setprio(1);                                             \
    _Pragma("unroll")                                                          \
    for (int i = 0; i < 4; ++i)                                                \
      _Pragma("unroll")                                                        \
      for (int j = 0; j < 4; ++j)                                              \
        acc0[i][j] = __builtin_amdgcn_mfma_f32_16x16x32_bf16(                  \
            afr[CUR][i], bf0r[CUR][j], acc0[i][j], 0, 0, 0);                   \
    __builtin_amdgcn_s_setprio(0);                                             \
    __builtin_amdgcn_sched_barrier(0);                                         \
    if (DO_PF) {                                                               \
      const unsigned short* bA_n = S + ((tau_ + 1) & 3) * 16384;               \
      _Pragma("unroll")                                                        \
      for (int i = 0; i < 4; ++i)                                              \
        afr[NXT][i] = *(const s8v*)(bA_n + aoff0 + i * 512);                   \
      _Pragma("unroll")                                                        \
      for (int j = 0; j < 4; ++j)                                              \
        bf0r[NXT][j] = *(const s8v*)(bA_n + 8192 + boffb + j * 512);           \
      __builtin_amdgcn_sched_barrier(0);                                       \
      asm volatile("s_waitcnt lgkmcnt(8)");                                    \
    } else {                                                                   \
      asm volatile("s_waitcnt lgkmcnt(0)");                                    \
    }                                                                          \
    __builtin_amdgcn_sched_barrier(0);                                         \
    __builtin_amdgcn_s_setprio(1);                                             \
    _Pragma("unroll")                                                          \
    for (int i = 0; i < 4; ++i)                                                \
      _Pragma("unroll")                                                        \
      for (int j = 0; j < 4; ++j)                                              \
        acc1[i][j] = __builtin_amdgcn_mfma_f32_16x16x32_bf16(                  \
            afr[CUR][i], b1f[j], acc1[i][j], 0, 0, 0);                         \
    __builtin_amdgcn_s_setprio(0);                                             \
    __builtin_amdgcn_sched_barrier(0);                                         \
    __builtin_amdgcn_s_barrier();                                              \
  }

__global__ __launch_bounds__(512, 2) void gemm_gated8(
        const unsigned short* __restrict__ Abf, const unsigned short* __restrict__ Wbf,
        const float* __restrict__ x, const float* __restrict__ avg,
        const float* __restrict__ bg, float* __restrict__ out) {
    __shared__ __attribute__((aligned(16))) unsigned short S[4 * 16384]; // 128 KiB

    const int t    = threadIdx.x;          // 0..511
    const int w    = t >> 6;               // 0..7
    const int lane = t & 63;
    const int wm = w >> 1, wn = w & 1;     // 4M x 2N wave grid
    const int quad = lane >> 4, lcol = lane & 15;

    const int bid = blockIdx.x;            // 512 blocks, bijective XCD swizzle
    const int swz = (bid & 7) * 64 + (bid >> 3);
    const int tileN = swz & 7, tileM = swz >> 3;
    const int row0 = tileM * 256, col0 = tileN * 128;

    f4v acc0[4][4], acc1[4][4];
#pragma unroll
    for (int i = 0; i < 4; ++i)
#pragma unroll
        for (int j = 0; j < 4; ++j)
#pragma unroll
            for (int r = 0; r < 4; ++r) { acc0[i][j][r] = 0.f; acc1[i][j][r] = 0.f; }

    // staging: thread t owns granules qA0=t, qA1=512+t; source granule
    // p = q ^ ((q>>3)&3). p1 = 512 + p0 -> second halves are constant offsets.
    const int qA0 = t, qA1 = 512 + t;
    const int p0 = qA0 ^ ((qA0 >> 3) & 3);
    const int m0 = p0 >> 2, k0e = (p0 & 3) * 8;     // m0 in [0,128)
    const unsigned short* gA0 = Abf + (size_t)(row0 + m0) * K2 + k0e;   // +262144 = rows+128
    const unsigned short* gB0 = Wbf + (size_t)(col0 + m0) * K2 + k0e;   // +2097152 = half1

    // LDS read bases (ushort idx), swizzle bits 3..4: ^ ((lcol>>1)&3)<<3
    const int swzx  = ((lcol >> 1) & 3) << 3;
    const int aoff0 = ((wm * 64 + lcol) * 32 + quad * 8) ^ swzx;  // + i*512
    const int boffb = ((wn * 64 + lcol) * 32 + quad * 8) ^ swzx;  // + j*512 (+4096 h1)

    // ---- prologue: stage tiles 0,1,2; prefetch frags(0) ----
#pragma unroll
    for (int tt = 0; tt < 3; ++tt) {
        unsigned short* dA = S + tt * 16384;
        const int ko = tt * 32;
        llds16(gA0 + ko, dA + qA0 * 8);
        llds16(gA0 + 262144 + ko, dA + qA1 * 8);
        llds16(gB0 + ko, dA + 8192 + qA0 * 8);
        llds16(gB0 + 2097152 + ko, dA + 8192 + qA1 * 8);
    }
    asm volatile("s_waitcnt vmcnt(8)" ::: "memory");  // tile 0 landed
    __builtin_amdgcn_s_barrier();

    s8v afr[2][4], bf0r[2][4];
#pragma unroll
    for (int i = 0; i < 4; ++i) afr[0][i] = *(const s8v*)(S + aoff0 + i * 512);
#pragma unroll
    for (int j = 0; j < 4; ++j) bf0r[0][j] = *(const s8v*)(S + 8192 + boffb + j * 512);
    __builtin_amdgcn_sched_barrier(0);

    // ---- main loop: 30 pairs (taus 0..59), then tail taus 60..63 ----
    for (int tp = 0; tp < 30; ++tp) {
        TAU_ITER(0, 1, 2 * tp,     true, true, "8");
        TAU_ITER(1, 0, 2 * tp + 1, true, true, "8");
    }
    TAU_ITER(0, 1, 60, true,  true,  "8");   // stages tile 63; retires 61
    TAU_ITER(1, 0, 61, false, true,  "4");   // retires 62
    TAU_ITER(0, 1, 62, false, true,  "0");   // retires 63
    TAU_ITER(1, 0, 63, false, false, "0");   // no prefetch

    // ---- epilogue: gating in-register. C/D: col = lane&15, row = quad*4+reg ----
    float b1v[4], b2v[4];
#pragma unroll
    for (int j = 0; j < 4; ++j) {
        int cc = col0 + wn * 64 + j * 16 + lcol;
        b1v[j] = bg[cc];
        b2v[j] = bg[1024 + cc];
    }
#pragma unroll
    for (int i = 0; i < 4; ++i) {
#pragma unroll
        for (int j = 0; j < 4; ++j) {
            int rr = row0 + wm * 64 + i * 16 + quad * 4;
            int cc = col0 + wn * 64 + j * 16 + lcol;
#pragma unroll
            for (int r = 0; r < 4; ++r) {
                size_t off = (size_t)(rr + r) * D_ + cc;
                float gi = sigmoidf_(acc0[i][j][r] + b1v[j]);
                float gf = sigmoidf_(acc1[i][j][r] + b2v[j]);
                out[off] = gi * x[off] + gf * avg[off];
            }
        }
    }
}

extern "C" void kernel_launch(void* const* d_in, const int* in_sizes, int n_in,
                              void* d_out, int out_size, void* d_ws, size_t ws_size,
                              hipStream_t stream) {
    const float* x  = (const float*)d_in[0];   // [4,4096,1024]
    const float* W  = (const float*)d_in[1];   // [2048,2048]
    const float* bg = (const float*)d_in[2];   // [2048]
    float* out = (float*)d_out;                // [BLD gating | BLD avg]
    float* avg = out + (size_t)BLD;

    char* ws = (char*)d_ws;
    unsigned short* Abf = (unsigned short*)(ws);                      // 64 MB [16384 x 2048] bf16
    unsigned short* Wbf = (unsigned short*)(ws + (size_t)67108864);   //  8 MB [2048 x 2048] bf16
    float4*         prt = (float4*)(ws + (size_t)75497472);           //  1 MB [B x NC x D] f32

    prep1<<<dim3(4352), dim3(256), 0, stream>>>((const float4*)x, prt,
                                                (const float4*)W, (ushort4*)Wbf);
    apply_scan<<<dim3(256), dim3(256), 0, stream>>>((const float4*)x, prt,
                                                    (float4*)avg, (ushort4*)Abf);
    gemm_gated8<<<dim3(512), dim3(512), 0, stream>>>(Abf, Wbf, x, avg, bg, out);
}